// Round 5
// baseline (394.887 us; speedup 1.0000x reference)
//
#include <hip/hip_runtime.h>

typedef float           f32x16  __attribute__((ext_vector_type(16)));
typedef float           f32x4   __attribute__((ext_vector_type(4)));
typedef __bf16          bf16x8  __attribute__((ext_vector_type(8)));
typedef unsigned short  ushort8 __attribute__((ext_vector_type(8)));
typedef unsigned int    uint4v  __attribute__((ext_vector_type(4)));

#define MFMA(a,b,c) __builtin_amdgcn_mfma_f32_32x32x16_bf16(a, b, c, 0, 0, 0)

static __device__ __forceinline__ unsigned fbits(float x) { return __builtin_bit_cast(unsigned, x); }
static __device__ __forceinline__ float    bitsf(unsigned u) { return __builtin_bit_cast(float, u); }

// split fp32 -> bf16 hi + bf16 lo (truncation; identical numerics to R2/R3)
static __device__ __forceinline__ void bsplit(float x, unsigned short& hi, unsigned short& lo) {
    unsigned u = fbits(x);
    hi = (unsigned short)(u >> 16);
    float rem = x - bitsf(u & 0xFFFF0000u);
    lo = (unsigned short)(fbits(rem) >> 16);
}

// pack hi16(e) | hi16(o)<<16 in one v_perm_b32
static __device__ __forceinline__ unsigned packhi(float e, float o) {
    return __builtin_amdgcn_perm(fbits(o), fbits(e), 0x07060302u);
}
static __device__ __forceinline__ float remf(float x) {
    return x - bitsf(fbits(x) & 0xFFFF0000u);
}

// LDS (byte): W1 frags 0..24575, W2 frags 24576..32767, b1 floats 32768..33279
__global__ __launch_bounds__(512, 8) void nca_mfma4_kernel(
    const float* __restrict__ grid,
    const float* __restrict__ W1, const float* __restrict__ b1,
    const float* __restrict__ W2, const float* __restrict__ b2,
    float* __restrict__ out)
{
    __shared__ unsigned short sLDS[16640];   // 33280 B
    float* sB1f = (float*)&sLDS[16384];

    const int tid  = threadIdx.x;
    const int l    = tid & 63;
    const int w    = tid >> 6;       // 0..7
    const int half = l >> 5;
    const int ol   = l & 31;

    // ---------------- stage W1 fragments (pre-split, lane-major; sobel /8 folded) ----------------
    for (int sidx = tid; sidx < 768; sidx += 512) {
        int ls   = sidx & 63;
        int fp   = sidx >> 6;            // 0..11 = og*3+kk
        int kk   = fp % 3;
        int o    = (fp/3)*32 + (ls & 31);
        int k0   = kk*16 + (ls>>5)*8;
        float sc = (kk == 0) ? 1.0f : 0.125f;
        ushort8 hi8, lo8;
        #pragma unroll
        for (int j = 0; j < 8; ++j) {
            unsigned short h, lo_;
            bsplit(W1[o*48 + k0 + j] * sc, h, lo_);
            hi8[j] = h; lo8[j] = lo_;
        }
        *(ushort8*)&sLDS[(fp*2 + 0)*512 + ls*8] = hi8;
        *(ushort8*)&sLDS[(fp*2 + 1)*512 + ls*8] = lo8;
    }

    // ---------------- stage W2 fragments ----------------
    if (tid < 256) {
        int kk2  = tid >> 5;             // 0..7
        int cidx = tid & 31;
        int o    = cidx & 15;
        int hs   = cidx >> 4;
        int k0   = kk2*16 + hs*8;
        ushort8 hi8, lo8;
        #pragma unroll
        for (int j = 0; j < 8; ++j) {
            unsigned short h, lo_;
            bsplit(W2[o*128 + k0 + j], h, lo_);
            hi8[j] = h; lo8[j] = lo_;
        }
        *(ushort8*)&sLDS[12288 + (kk2*2 + 0)*256 + cidx*8] = hi8;
        *(ushort8*)&sLDS[12288 + (kk2*2 + 1)*256 + cidx*8] = lo8;
    }

    if (tid < 128) sB1f[tid] = b1[tid];

    const bool  v16 = (ol < 16);
    const float b2v = v16 ? b2[ol] : 0.0f;

    __syncthreads();

    const int w1a = l*16;                                  // + frag*1024 byte imm
    const int w2a = 24576 + ((ol & 15) + (half << 4))*16;  // + frag*512 byte imm
    const int b1a = 4*half;                                // float-index base

    const auto ld8 = [&](int byteoff) -> ushort8 {
        return *(const ushort8*)((const char*)sLDS + byteoff);
    };

    // ---------------- XCD-chunked swizzle: 1024 blocks, 128 contiguous per XCD ----------------
    const int bid  = blockIdx.x;
    const int wgid = ((bid & 7) << 7) | (bid >> 3);

    const int gw = wgid*8 + w;            // 8192 waves
    const int t0 = gw*4;
    const int y  = (t0 >> 3) & 255;
    const int b  =  t0 >> 11;
    const int dyt = (y > 0)   ? -256 : 0;
    const int dyb = (y < 255) ?  256 : 0;
    const float fmt = (y > 0)   ? 1.f : 0.f;
    const float fmb = (y < 255) ? 1.f : 0.f;

    for (int i = 0; i < 4; ++i) {
        const int t  = t0 + i;
        const int x0 = (t & 7) << 5;
        const int x  = x0 + ol;

        // opaque copies of LDS bases: defeat LICM/CSE of weight loads across tiles
        int w1ai = w1a, w2ai = w2a, b1ai = b1a;
        asm volatile("" : "+v"(w1ai), "+v"(w2ai), "+v"(b1ai));

        bf16x8 pah[3], pal[3];

        const bool interior = (x0 != 0) && (x0 != 224) && (y != 0) && (y != 255);
        if (interior) {
            // ---- fast path: one address/ch-pair, 9 imm-offset taps, no masks ----
            const float* p = grid + ((b*16 + half*8)*65536 + y*256 + x);
            unsigned A[3][4], L[3][4];
            #pragma unroll
            for (int cp = 0; cp < 4; ++cp) {
                const float* pe = p;
                const float* po = p + 65536;
                float e00 = pe[-257], e01 = pe[-256], e02 = pe[-255];
                float e10 = pe[-1],   e11 = pe[0],    e12 = pe[1];
                float e20 = pe[255],  e21 = pe[256],  e22 = pe[257];
                float o00 = po[-257], o01 = po[-256], o02 = po[-255];
                float o10 = po[-1],   o11 = po[0],    o12 = po[1];
                float o20 = po[255],  o21 = po[256],  o22 = po[257];
                float esx = (e02 - e00) + 2.f*(e12 - e10) + (e22 - e20);
                float esy = (e20 - e00) + 2.f*(e21 - e01) + (e22 - e02);
                float osx = (o02 - o00) + 2.f*(o12 - o10) + (o22 - o20);
                float osy = (o20 - o00) + 2.f*(o21 - o01) + (o22 - o02);
                A[0][cp] = packhi(e11, o11); L[0][cp] = packhi(remf(e11), remf(o11));
                A[1][cp] = packhi(esx, osx); L[1][cp] = packhi(remf(esx), remf(osx));
                A[2][cp] = packhi(esy, osy); L[2][cp] = packhi(remf(esy), remf(osy));
                p += 2*65536;
            }
            #pragma unroll
            for (int kk = 0; kk < 3; ++kk) {
                uint4v ha = { A[kk][0], A[kk][1], A[kk][2], A[kk][3] };
                uint4v la = { L[kk][0], L[kk][1], L[kk][2], L[kk][3] };
                pah[kk] = __builtin_bit_cast(bf16x8, ha);
                pal[kk] = __builtin_bit_cast(bf16x8, la);
            }
        } else {
            // ---- edge path: masked, clamped (R3 code) ----
            const int   dxl = (x > 0)   ? -1 : 0;
            const int   dxr = (x < 255) ?  1 : 0;
            const float fml = (x > 0)   ? 1.f : 0.f;
            const float fmr = (x < 255) ? 1.f : 0.f;
            const float ftl = fml*fmt, ftr = fmr*fmt, fbl = fml*fmb, fbr = fmr*fmb;

            const int pbase = (b*16 + half*8)*65536 + y*256 + x;
            ushort8 ahi[3], alo[3];
            #pragma unroll
            for (int ci = 0; ci < 8; ++ci) {
                int ic = pbase + ci*65536;
                int it = ic + dyt, ib = ic + dyb;
                float v00 = grid[it + dxl]*ftl, v01 = grid[it]*fmt, v02 = grid[it + dxr]*ftr;
                float v10 = grid[ic + dxl]*fml, v11 = grid[ic],     v12 = grid[ic + dxr]*fmr;
                float v20 = grid[ib + dxl]*fbl, v21 = grid[ib]*fmb, v22 = grid[ib + dxr]*fbr;
                float sx = (v02 - v00) + 2.f*(v12 - v10) + (v22 - v20);
                float sy = (v20 - v00) + 2.f*(v21 - v01) + (v22 - v02);
                unsigned short h, lo_;
                bsplit(v11, h, lo_); ahi[0][ci] = h; alo[0][ci] = lo_;
                bsplit(sx,  h, lo_); ahi[1][ci] = h; alo[1][ci] = lo_;
                bsplit(sy,  h, lo_); ahi[2][ci] = h; alo[2][ci] = lo_;
            }
            #pragma unroll
            for (int kk = 0; kk < 3; ++kk) {
                pah[kk] = __builtin_bit_cast(bf16x8, ahi[kk]);
                pal[kk] = __builtin_bit_cast(bf16x8, alo[kk]);
            }
        }

        // ---- fused MLP via MFMA (GEMM1 pixel-major out, permlane swap, GEMM2) ----
        f32x16 acc2;
        #pragma unroll
        for (int r = 0; r < 16; ++r) acc2[r] = b2v;

        #pragma unroll
        for (int og = 0; og < 4; ++og) {
            f32x16 acc1;
            #pragma unroll
            for (int T = 0; T < 4; ++T) {
                f32x4 q = *(const f32x4*)&sB1f[b1ai + og*32 + 8*T];
                acc1[4*T+0] = q[0]; acc1[4*T+1] = q[1];
                acc1[4*T+2] = q[2]; acc1[4*T+3] = q[3];
            }

            #pragma unroll
            for (int kk = 0; kk < 3; ++kk) {
                bf16x8 w_h = __builtin_bit_cast(bf16x8, ld8(w1ai + ((og*3 + kk)*2 + 0)*1024));
                bf16x8 w_l = __builtin_bit_cast(bf16x8, ld8(w1ai + ((og*3 + kk)*2 + 1)*1024));
                acc1 = MFMA(w_h, pah[kk], acc1);
                acc1 = MFMA(w_h, pal[kk], acc1);
                acc1 = MFMA(w_l, pah[kk], acc1);
            }

            // relu + hi/lo split + pack pairs (dword d holds elems 2d,2d+1)
            unsigned Phi[8], Plo[8];
            #pragma unroll
            for (int T = 0; T < 4; ++T) {
                float h0 = fmaxf(acc1[4*T+0], 0.f), h1 = fmaxf(acc1[4*T+1], 0.f);
                float h2 = fmaxf(acc1[4*T+2], 0.f), h3 = fmaxf(acc1[4*T+3], 0.f);
                Phi[2*T+0] = packhi(h0, h1);
                Phi[2*T+1] = packhi(h2, h3);
                Plo[2*T+0] = packhi(remf(h0), remf(h1));
                Plo[2*T+1] = packhi(remf(h2), remf(h3));
            }

            // half-swap -> GEMM2 A-fragments (lane = pixel row, k = hidden)
            #pragma unroll
            for (int c = 0; c < 2; ++c) {
                unsigned fa0 = Phi[(2*c)*2+0], fb0 = Phi[(2*c+1)*2+0];
                unsigned fa1 = Phi[(2*c)*2+1], fb1 = Phi[(2*c+1)*2+1];
                asm volatile("v_permlane32_swap_b32 %0, %1" : "+v"(fa0), "+v"(fb0));
                asm volatile("v_permlane32_swap_b32 %0, %1" : "+v"(fa1), "+v"(fb1));
                unsigned la0 = Plo[(2*c)*2+0], lb0 = Plo[(2*c+1)*2+0];
                unsigned la1 = Plo[(2*c)*2+1], lb1 = Plo[(2*c+1)*2+1];
                asm volatile("v_permlane32_swap_b32 %0, %1" : "+v"(la0), "+v"(lb0));
                asm volatile("v_permlane32_swap_b32 %0, %1" : "+v"(la1), "+v"(lb1));
                uint4v hv_ = { fa0, fa1, fb0, fb1 };
                uint4v lv_ = { la0, la1, lb0, lb1 };
                bf16x8 A2h = __builtin_bit_cast(bf16x8, hv_);
                bf16x8 A2l = __builtin_bit_cast(bf16x8, lv_);

                const int g = (og*2 + c)*2;
                bf16x8 w2h = __builtin_bit_cast(bf16x8, ld8(w2ai + (g + 0)*512));
                bf16x8 w2l = __builtin_bit_cast(bf16x8, ld8(w2ai + (g + 1)*512));
                acc2 = MFMA(A2h, w2h, acc2);
                acc2 = MFMA(A2h, w2l, acc2);
                acc2 = MFMA(A2l, w2h, acc2);
            }
        }

        // ---- store: lane ol(<16) = out-channel; regs = 16 pixels as 4x float4 ----
        if (v16) {
            const int ob = (b*16 + ol)*65536 + y*256 + x0 + half*4;
            #pragma unroll
            for (int c = 0; c < 4; ++c) {
                f32x4 v = { acc2[4*c+0], acc2[4*c+1], acc2[4*c+2], acc2[4*c+3] };
                *(f32x4*)&out[ob + c*8] = v;
            }
        }
    }
}

extern "C" void kernel_launch(void* const* d_in, const int* in_sizes, int n_in,
                              void* d_out, int out_size, void* d_ws, size_t ws_size,
                              hipStream_t stream) {
    const float* grid = (const float*)d_in[0];
    const float* W1   = (const float*)d_in[1];
    const float* b1   = (const float*)d_in[2];
    const float* W2   = (const float*)d_in[3];
    const float* b2   = (const float*)d_in[4];
    float* out = (float*)d_out;

    // 1024 blocks x 512 threads = 8192 waves; each wave: 4 tiles of 32 pixels
    nca_mfma4_kernel<<<1024, 512, 0, stream>>>(grid, W1, b1, W2, b2, out);
}

// Round 9
// 261.443 us; speedup vs baseline: 1.5104x; 1.5104x over previous
//
#include <hip/hip_runtime.h>

typedef float           f32x16  __attribute__((ext_vector_type(16)));
typedef float           f32x4   __attribute__((ext_vector_type(4)));
typedef __bf16          bf16x8  __attribute__((ext_vector_type(8)));
typedef unsigned short  ushort8 __attribute__((ext_vector_type(8)));
typedef unsigned int    uint4v  __attribute__((ext_vector_type(4)));

#define MFMA(a,b,c) __builtin_amdgcn_mfma_f32_32x32x16_bf16(a, b, c, 0, 0, 0)

static __device__ __forceinline__ unsigned fbits(float x) { return __builtin_bit_cast(unsigned, x); }
static __device__ __forceinline__ float    bitsf(unsigned u) { return __builtin_bit_cast(float, u); }

// split fp32 -> bf16 hi + bf16 lo (truncation; identical numerics to R2/R3)
static __device__ __forceinline__ void bsplit(float x, unsigned short& hi, unsigned short& lo) {
    unsigned u = fbits(x);
    hi = (unsigned short)(u >> 16);
    float rem = x - bitsf(u & 0xFFFF0000u);
    lo = (unsigned short)(fbits(rem) >> 16);
}

// pack hi16(e) | hi16(o)<<16 in one v_perm_b32
static __device__ __forceinline__ unsigned packhi(float e, float o) {
    return __builtin_amdgcn_perm(fbits(o), fbits(e), 0x07060302u);
}
static __device__ __forceinline__ float remf(float x) {
    return x - bitsf(fbits(x) & 0xFFFF0000u);
}

// LDS (byte): W1 frags 0..24575, W2 frags 24576..32767, b1 floats 32768..33279
// launch_bounds (512,6): VGPR cap ~84 — (512,8)'s 64-cap caused a spill
// catastrophe in R5 (FETCH+WRITE ~1 GB of scratch, 3x regression).
__global__ __launch_bounds__(512, 6) void nca_mfma5_kernel(
    const float* __restrict__ grid,
    const float* __restrict__ W1, const float* __restrict__ b1,
    const float* __restrict__ W2, const float* __restrict__ b2,
    float* __restrict__ out)
{
    __shared__ unsigned short sLDS[16640];   // 33280 B
    float* sB1f = (float*)&sLDS[16384];

    const int tid  = threadIdx.x;
    const int l    = tid & 63;
    const int w    = tid >> 6;       // 0..7
    const int half = l >> 5;
    const int ol   = l & 31;

    // ---------------- stage W1 fragments (pre-split, lane-major; sobel /8 folded) ----------------
    for (int sidx = tid; sidx < 768; sidx += 512) {
        int ls   = sidx & 63;
        int fp   = sidx >> 6;            // 0..11 = og*3+kk
        int kk   = fp % 3;
        int o    = (fp/3)*32 + (ls & 31);
        int k0   = kk*16 + (ls>>5)*8;
        float sc = (kk == 0) ? 1.0f : 0.125f;
        ushort8 hi8, lo8;
        #pragma unroll
        for (int j = 0; j < 8; ++j) {
            unsigned short h, lo_;
            bsplit(W1[o*48 + k0 + j] * sc, h, lo_);
            hi8[j] = h; lo8[j] = lo_;
        }
        *(ushort8*)&sLDS[(fp*2 + 0)*512 + ls*8] = hi8;
        *(ushort8*)&sLDS[(fp*2 + 1)*512 + ls*8] = lo8;
    }

    // ---------------- stage W2 fragments ----------------
    if (tid < 256) {
        int kk2  = tid >> 5;             // 0..7
        int cidx = tid & 31;
        int o    = cidx & 15;
        int hs   = cidx >> 4;
        int k0   = kk2*16 + hs*8;
        ushort8 hi8, lo8;
        #pragma unroll
        for (int j = 0; j < 8; ++j) {
            unsigned short h, lo_;
            bsplit(W2[o*128 + k0 + j], h, lo_);
            hi8[j] = h; lo8[j] = lo_;
        }
        *(ushort8*)&sLDS[12288 + (kk2*2 + 0)*256 + cidx*8] = hi8;
        *(ushort8*)&sLDS[12288 + (kk2*2 + 1)*256 + cidx*8] = lo8;
    }

    if (tid < 128) sB1f[tid] = b1[tid];

    const bool  v16 = (ol < 16);
    const float b2v = v16 ? b2[ol] : 0.0f;

    __syncthreads();

    const int w1a = l*16;                                  // + frag*1024 byte imm
    const int w2a = 24576 + ((ol & 15) + (half << 4))*16;  // + frag*512 byte imm
    const int b1a = 4*half;                                // float-index base

    const auto ld8 = [&](int byteoff) -> ushort8 {
        return *(const ushort8*)((const char*)sLDS + byteoff);
    };

    // ---------------- XCD-chunked swizzle: 1024 blocks, 128 contiguous per XCD ----------------
    const int bid  = blockIdx.x;
    const int wgid = ((bid & 7) << 7) | (bid >> 3);

    const int gw = wgid*8 + w;            // 8192 waves
    const int t0 = gw*4;
    const int y  = (t0 >> 3) & 255;
    const int b  =  t0 >> 11;
    const int dyt = (y > 0)   ? -256 : 0;
    const int dyb = (y < 255) ?  256 : 0;
    const float fmt = (y > 0)   ? 1.f : 0.f;
    const float fmb = (y < 255) ? 1.f : 0.f;

    for (int i = 0; i < 4; ++i) {
        const int t  = t0 + i;
        const int x0 = (t & 7) << 5;
        const int x  = x0 + ol;

        // opaque copies of LDS bases: defeat LICM/CSE of weight loads across tiles
        int w1ai = w1a, w2ai = w2a, b1ai = b1a;
        asm volatile("" : "+v"(w1ai), "+v"(w2ai), "+v"(b1ai));

        bf16x8 pah[3], pal[3];

        const bool interior = (x0 != 0) && (x0 != 224) && (y != 0) && (y != 255);
        if (interior) {
            // ---- fast path: one address/ch-pair, 9 imm-offset taps, no masks ----
            const float* p = grid + ((b*16 + half*8)*65536 + y*256 + x);
            unsigned A[3][4], L[3][4];
            #pragma unroll
            for (int cp = 0; cp < 4; ++cp) {
                const float* pe = p;
                const float* po = p + 65536;
                float e00 = pe[-257], e01 = pe[-256], e02 = pe[-255];
                float e10 = pe[-1],   e11 = pe[0],    e12 = pe[1];
                float e20 = pe[255],  e21 = pe[256],  e22 = pe[257];
                float o00 = po[-257], o01 = po[-256], o02 = po[-255];
                float o10 = po[-1],   o11 = po[0],    o12 = po[1];
                float o20 = po[255],  o21 = po[256],  o22 = po[257];
                float esx = (e02 - e00) + 2.f*(e12 - e10) + (e22 - e20);
                float esy = (e20 - e00) + 2.f*(e21 - e01) + (e22 - e02);
                float osx = (o02 - o00) + 2.f*(o12 - o10) + (o22 - o20);
                float osy = (o20 - o00) + 2.f*(o21 - o01) + (o22 - o02);
                A[0][cp] = packhi(e11, o11); L[0][cp] = packhi(remf(e11), remf(o11));
                A[1][cp] = packhi(esx, osx); L[1][cp] = packhi(remf(esx), remf(osx));
                A[2][cp] = packhi(esy, osy); L[2][cp] = packhi(remf(esy), remf(osy));
                p += 2*65536;
            }
            #pragma unroll
            for (int kk = 0; kk < 3; ++kk) {
                uint4v ha = { A[kk][0], A[kk][1], A[kk][2], A[kk][3] };
                uint4v la = { L[kk][0], L[kk][1], L[kk][2], L[kk][3] };
                pah[kk] = __builtin_bit_cast(bf16x8, ha);
                pal[kk] = __builtin_bit_cast(bf16x8, la);
            }
        } else {
            // ---- edge path: masked, clamped (R3 code) ----
            const int   dxl = (x > 0)   ? -1 : 0;
            const int   dxr = (x < 255) ?  1 : 0;
            const float fml = (x > 0)   ? 1.f : 0.f;
            const float fmr = (x < 255) ? 1.f : 0.f;
            const float ftl = fml*fmt, ftr = fmr*fmt, fbl = fml*fmb, fbr = fmr*fmb;

            const int pbase = (b*16 + half*8)*65536 + y*256 + x;
            ushort8 ahi[3], alo[3];
            #pragma unroll
            for (int ci = 0; ci < 8; ++ci) {
                int ic = pbase + ci*65536;
                int it = ic + dyt, ib = ic + dyb;
                float v00 = grid[it + dxl]*ftl, v01 = grid[it]*fmt, v02 = grid[it + dxr]*ftr;
                float v10 = grid[ic + dxl]*fml, v11 = grid[ic],     v12 = grid[ic + dxr]*fmr;
                float v20 = grid[ib + dxl]*fbl, v21 = grid[ib]*fmb, v22 = grid[ib + dxr]*fbr;
                float sx = (v02 - v00) + 2.f*(v12 - v10) + (v22 - v20);
                float sy = (v20 - v00) + 2.f*(v21 - v01) + (v22 - v02);
                unsigned short h, lo_;
                bsplit(v11, h, lo_); ahi[0][ci] = h; alo[0][ci] = lo_;
                bsplit(sx,  h, lo_); ahi[1][ci] = h; alo[1][ci] = lo_;
                bsplit(sy,  h, lo_); ahi[2][ci] = h; alo[2][ci] = lo_;
            }
            #pragma unroll
            for (int kk = 0; kk < 3; ++kk) {
                pah[kk] = __builtin_bit_cast(bf16x8, ahi[kk]);
                pal[kk] = __builtin_bit_cast(bf16x8, alo[kk]);
            }
        }

        // ---- fused MLP via MFMA (GEMM1 pixel-major out, permlane swap, GEMM2) ----
        f32x16 acc2;
        #pragma unroll
        for (int r = 0; r < 16; ++r) acc2[r] = b2v;

        #pragma unroll
        for (int og = 0; og < 4; ++og) {
            f32x16 acc1;
            #pragma unroll
            for (int T = 0; T < 4; ++T) {
                f32x4 q = *(const f32x4*)&sB1f[b1ai + og*32 + 8*T];
                acc1[4*T+0] = q[0]; acc1[4*T+1] = q[1];
                acc1[4*T+2] = q[2]; acc1[4*T+3] = q[3];
            }

            #pragma unroll
            for (int kk = 0; kk < 3; ++kk) {
                bf16x8 w_h = __builtin_bit_cast(bf16x8, ld8(w1ai + ((og*3 + kk)*2 + 0)*1024));
                bf16x8 w_l = __builtin_bit_cast(bf16x8, ld8(w1ai + ((og*3 + kk)*2 + 1)*1024));
                acc1 = MFMA(w_h, pah[kk], acc1);
                acc1 = MFMA(w_h, pal[kk], acc1);
                acc1 = MFMA(w_l, pah[kk], acc1);
            }

            // relu + hi/lo split + pack pairs (dword d holds elems 2d,2d+1)
            unsigned Phi[8], Plo[8];
            #pragma unroll
            for (int T = 0; T < 4; ++T) {
                float h0 = fmaxf(acc1[4*T+0], 0.f), h1 = fmaxf(acc1[4*T+1], 0.f);
                float h2 = fmaxf(acc1[4*T+2], 0.f), h3 = fmaxf(acc1[4*T+3], 0.f);
                Phi[2*T+0] = packhi(h0, h1);
                Phi[2*T+1] = packhi(h2, h3);
                Plo[2*T+0] = packhi(remf(h0), remf(h1));
                Plo[2*T+1] = packhi(remf(h2), remf(h3));
            }

            // half-swap -> GEMM2 A-fragments (lane = pixel row, k = hidden)
            #pragma unroll
            for (int c = 0; c < 2; ++c) {
                unsigned fa0 = Phi[(2*c)*2+0], fb0 = Phi[(2*c+1)*2+0];
                unsigned fa1 = Phi[(2*c)*2+1], fb1 = Phi[(2*c+1)*2+1];
                asm volatile("v_permlane32_swap_b32 %0, %1" : "+v"(fa0), "+v"(fb0));
                asm volatile("v_permlane32_swap_b32 %0, %1" : "+v"(fa1), "+v"(fb1));
                unsigned la0 = Plo[(2*c)*2+0], lb0 = Plo[(2*c+1)*2+0];
                unsigned la1 = Plo[(2*c)*2+1], lb1 = Plo[(2*c+1)*2+1];
                asm volatile("v_permlane32_swap_b32 %0, %1" : "+v"(la0), "+v"(lb0));
                asm volatile("v_permlane32_swap_b32 %0, %1" : "+v"(la1), "+v"(lb1));
                uint4v hv_ = { fa0, fa1, fb0, fb1 };
                uint4v lv_ = { la0, la1, lb0, lb1 };
                bf16x8 A2h = __builtin_bit_cast(bf16x8, hv_);
                bf16x8 A2l = __builtin_bit_cast(bf16x8, lv_);

                const int g = (og*2 + c)*2;
                bf16x8 w2h = __builtin_bit_cast(bf16x8, ld8(w2ai + (g + 0)*512));
                bf16x8 w2l = __builtin_bit_cast(bf16x8, ld8(w2ai + (g + 1)*512));
                acc2 = MFMA(A2h, w2h, acc2);
                acc2 = MFMA(A2h, w2l, acc2);
                acc2 = MFMA(A2l, w2h, acc2);
            }
        }

        // ---- store: lane ol(<16) = out-channel; regs = 16 pixels as 4x float4 ----
        if (v16) {
            const int ob = (b*16 + ol)*65536 + y*256 + x0 + half*4;
            #pragma unroll
            for (int c = 0; c < 4; ++c) {
                f32x4 v = { acc2[4*c+0], acc2[4*c+1], acc2[4*c+2], acc2[4*c+3] };
                *(f32x4*)&out[ob + c*8] = v;
            }
        }
    }
}

extern "C" void kernel_launch(void* const* d_in, const int* in_sizes, int n_in,
                              void* d_out, int out_size, void* d_ws, size_t ws_size,
                              hipStream_t stream) {
    const float* grid = (const float*)d_in[0];
    const float* W1   = (const float*)d_in[1];
    const float* b1   = (const float*)d_in[2];
    const float* W2   = (const float*)d_in[3];
    const float* b2   = (const float*)d_in[4];
    float* out = (float*)d_out;

    // 1024 blocks x 512 threads = 8192 waves; each wave: 4 tiles of 32 pixels
    nca_mfma5_kernel<<<1024, 512, 0, stream>>>(grid, W1, b1, W2, b2, out);
}

// Round 11
// 173.268 us; speedup vs baseline: 2.2790x; 1.5089x over previous
//
#include <hip/hip_runtime.h>

typedef float           f32x16  __attribute__((ext_vector_type(16)));
typedef float           f32x4   __attribute__((ext_vector_type(4)));
typedef __bf16          bf16x8  __attribute__((ext_vector_type(8)));
typedef unsigned short  ushort8 __attribute__((ext_vector_type(8)));
typedef unsigned int    uint4v  __attribute__((ext_vector_type(4)));

#define MFMA(a,b,c) __builtin_amdgcn_mfma_f32_32x32x16_bf16(a, b, c, 0, 0, 0)

static __device__ __forceinline__ unsigned fbits(float x) { return __builtin_bit_cast(unsigned, x); }
static __device__ __forceinline__ float    bitsf(unsigned u) { return __builtin_bit_cast(float, u); }

// split fp32 -> bf16 hi + bf16 lo (truncation; identical numerics to R2/R3)
static __device__ __forceinline__ void bsplit(float x, unsigned short& hi, unsigned short& lo) {
    unsigned u = fbits(x);
    hi = (unsigned short)(u >> 16);
    float rem = x - bitsf(u & 0xFFFF0000u);
    lo = (unsigned short)(fbits(rem) >> 16);
}

// pack hi16(e) | hi16(o)<<16 in one v_perm_b32
static __device__ __forceinline__ unsigned packhi(float e, float o) {
    return __builtin_amdgcn_perm(fbits(o), fbits(e), 0x07060302u);
}
static __device__ __forceinline__ float remf(float x) {
    return x - bitsf(fbits(x) & 0xFFFF0000u);
}

// LDS (byte): W1 frags 0..24575, W2 frags 24576..32767, b1 floats 32768..33279
// VGPR history (VGPR_Count is 2-reg granules): (512,8) cap64 -> pinned 32, ~1GB
// scratch (R5); (512,6) cap80 -> pinned 40, ~390MB scratch (R9). Kernel needs
// ~120 regs -> (512,4) cap128. Occupancy: 512/120 = 4 waves/SIMD = 50%, 2
// blocks/CU, spill-free. 512-thr blocks amortize LDS (vs R3's 3x256thr=37.5%).
__global__ __launch_bounds__(512, 4) void nca_mfma6_kernel(
    const float* __restrict__ grid,
    const float* __restrict__ W1, const float* __restrict__ b1,
    const float* __restrict__ W2, const float* __restrict__ b2,
    float* __restrict__ out)
{
    __shared__ unsigned short sLDS[16640];   // 33280 B
    float* sB1f = (float*)&sLDS[16384];

    const int tid  = threadIdx.x;
    const int l    = tid & 63;
    const int w    = tid >> 6;       // 0..7
    const int half = l >> 5;
    const int ol   = l & 31;

    // ---------------- stage W1 fragments (pre-split, lane-major; sobel /8 folded) ----------------
    for (int sidx = tid; sidx < 768; sidx += 512) {
        int ls   = sidx & 63;
        int fp   = sidx >> 6;            // 0..11 = og*3+kk
        int kk   = fp % 3;
        int o    = (fp/3)*32 + (ls & 31);
        int k0   = kk*16 + (ls>>5)*8;
        float sc = (kk == 0) ? 1.0f : 0.125f;
        ushort8 hi8, lo8;
        #pragma unroll
        for (int j = 0; j < 8; ++j) {
            unsigned short h, lo_;
            bsplit(W1[o*48 + k0 + j] * sc, h, lo_);
            hi8[j] = h; lo8[j] = lo_;
        }
        *(ushort8*)&sLDS[(fp*2 + 0)*512 + ls*8] = hi8;
        *(ushort8*)&sLDS[(fp*2 + 1)*512 + ls*8] = lo8;
    }

    // ---------------- stage W2 fragments ----------------
    if (tid < 256) {
        int kk2  = tid >> 5;             // 0..7
        int cidx = tid & 31;
        int o    = cidx & 15;
        int hs   = cidx >> 4;
        int k0   = kk2*16 + hs*8;
        ushort8 hi8, lo8;
        #pragma unroll
        for (int j = 0; j < 8; ++j) {
            unsigned short h, lo_;
            bsplit(W2[o*128 + k0 + j], h, lo_);
            hi8[j] = h; lo8[j] = lo_;
        }
        *(ushort8*)&sLDS[12288 + (kk2*2 + 0)*256 + cidx*8] = hi8;
        *(ushort8*)&sLDS[12288 + (kk2*2 + 1)*256 + cidx*8] = lo8;
    }

    if (tid < 128) sB1f[tid] = b1[tid];

    const bool  v16 = (ol < 16);
    const float b2v = v16 ? b2[ol] : 0.0f;

    __syncthreads();

    const int w1a = l*16;                                  // + frag*1024 byte imm
    const int w2a = 24576 + ((ol & 15) + (half << 4))*16;  // + frag*512 byte imm
    const int b1a = 4*half;                                // float-index base

    const auto ld8 = [&](int byteoff) -> ushort8 {
        return *(const ushort8*)((const char*)sLDS + byteoff);
    };

    // ---------------- XCD-chunked swizzle: 1024 blocks, 128 contiguous per XCD ----------------
    const int bid  = blockIdx.x;
    const int wgid = ((bid & 7) << 7) | (bid >> 3);

    const int gw = wgid*8 + w;            // 8192 waves
    const int t0 = gw*4;
    const int y  = (t0 >> 3) & 255;
    const int b  =  t0 >> 11;
    const int dyt = (y > 0)   ? -256 : 0;
    const int dyb = (y < 255) ?  256 : 0;
    const float fmt = (y > 0)   ? 1.f : 0.f;
    const float fmb = (y < 255) ? 1.f : 0.f;

    for (int i = 0; i < 4; ++i) {
        const int t  = t0 + i;
        const int x0 = (t & 7) << 5;
        const int x  = x0 + ol;

        // opaque copies of LDS bases: defeat LICM/CSE of weight loads across tiles
        int w1ai = w1a, w2ai = w2a, b1ai = b1a;
        asm volatile("" : "+v"(w1ai), "+v"(w2ai), "+v"(b1ai));

        bf16x8 pah[3], pal[3];

        const bool interior = (x0 != 0) && (x0 != 224) && (y != 0) && (y != 255);
        if (interior) {
            // ---- fast path: one address/ch-pair, 9 imm-offset taps, no masks ----
            const float* p = grid + ((b*16 + half*8)*65536 + y*256 + x);
            unsigned A[3][4], L[3][4];
            #pragma unroll
            for (int cp = 0; cp < 4; ++cp) {
                const float* pe = p;
                const float* po = p + 65536;
                float e00 = pe[-257], e01 = pe[-256], e02 = pe[-255];
                float e10 = pe[-1],   e11 = pe[0],    e12 = pe[1];
                float e20 = pe[255],  e21 = pe[256],  e22 = pe[257];
                float o00 = po[-257], o01 = po[-256], o02 = po[-255];
                float o10 = po[-1],   o11 = po[0],    o12 = po[1];
                float o20 = po[255],  o21 = po[256],  o22 = po[257];
                float esx = (e02 - e00) + 2.f*(e12 - e10) + (e22 - e20);
                float esy = (e20 - e00) + 2.f*(e21 - e01) + (e22 - e02);
                float osx = (o02 - o00) + 2.f*(o12 - o10) + (o22 - o20);
                float osy = (o20 - o00) + 2.f*(o21 - o01) + (o22 - o02);
                A[0][cp] = packhi(e11, o11); L[0][cp] = packhi(remf(e11), remf(o11));
                A[1][cp] = packhi(esx, osx); L[1][cp] = packhi(remf(esx), remf(osx));
                A[2][cp] = packhi(esy, osy); L[2][cp] = packhi(remf(esy), remf(osy));
                p += 2*65536;
            }
            #pragma unroll
            for (int kk = 0; kk < 3; ++kk) {
                uint4v ha = { A[kk][0], A[kk][1], A[kk][2], A[kk][3] };
                uint4v la = { L[kk][0], L[kk][1], L[kk][2], L[kk][3] };
                pah[kk] = __builtin_bit_cast(bf16x8, ha);
                pal[kk] = __builtin_bit_cast(bf16x8, la);
            }
        } else {
            // ---- edge path: masked, clamped (R3 code) ----
            const int   dxl = (x > 0)   ? -1 : 0;
            const int   dxr = (x < 255) ?  1 : 0;
            const float fml = (x > 0)   ? 1.f : 0.f;
            const float fmr = (x < 255) ? 1.f : 0.f;
            const float ftl = fml*fmt, ftr = fmr*fmt, fbl = fml*fmb, fbr = fmr*fmb;

            const int pbase = (b*16 + half*8)*65536 + y*256 + x;
            ushort8 ahi[3], alo[3];
            #pragma unroll
            for (int ci = 0; ci < 8; ++ci) {
                int ic = pbase + ci*65536;
                int it = ic + dyt, ib = ic + dyb;
                float v00 = grid[it + dxl]*ftl, v01 = grid[it]*fmt, v02 = grid[it + dxr]*ftr;
                float v10 = grid[ic + dxl]*fml, v11 = grid[ic],     v12 = grid[ic + dxr]*fmr;
                float v20 = grid[ib + dxl]*fbl, v21 = grid[ib]*fmb, v22 = grid[ib + dxr]*fbr;
                float sx = (v02 - v00) + 2.f*(v12 - v10) + (v22 - v20);
                float sy = (v20 - v00) + 2.f*(v21 - v01) + (v22 - v02);
                unsigned short h, lo_;
                bsplit(v11, h, lo_); ahi[0][ci] = h; alo[0][ci] = lo_;
                bsplit(sx,  h, lo_); ahi[1][ci] = h; alo[1][ci] = lo_;
                bsplit(sy,  h, lo_); ahi[2][ci] = h; alo[2][ci] = lo_;
            }
            #pragma unroll
            for (int kk = 0; kk < 3; ++kk) {
                pah[kk] = __builtin_bit_cast(bf16x8, ahi[kk]);
                pal[kk] = __builtin_bit_cast(bf16x8, alo[kk]);
            }
        }

        // ---- fused MLP via MFMA (GEMM1 pixel-major out, permlane swap, GEMM2) ----
        f32x16 acc2;
        #pragma unroll
        for (int r = 0; r < 16; ++r) acc2[r] = b2v;

        #pragma unroll
        for (int og = 0; og < 4; ++og) {
            f32x16 acc1;
            #pragma unroll
            for (int T = 0; T < 4; ++T) {
                f32x4 q = *(const f32x4*)&sB1f[b1ai + og*32 + 8*T];
                acc1[4*T+0] = q[0]; acc1[4*T+1] = q[1];
                acc1[4*T+2] = q[2]; acc1[4*T+3] = q[3];
            }

            #pragma unroll
            for (int kk = 0; kk < 3; ++kk) {
                bf16x8 w_h = __builtin_bit_cast(bf16x8, ld8(w1ai + ((og*3 + kk)*2 + 0)*1024));
                bf16x8 w_l = __builtin_bit_cast(bf16x8, ld8(w1ai + ((og*3 + kk)*2 + 1)*1024));
                acc1 = MFMA(w_h, pah[kk], acc1);
                acc1 = MFMA(w_h, pal[kk], acc1);
                acc1 = MFMA(w_l, pah[kk], acc1);
            }

            // relu + hi/lo split + pack pairs (dword d holds elems 2d,2d+1)
            unsigned Phi[8], Plo[8];
            #pragma unroll
            for (int T = 0; T < 4; ++T) {
                float h0 = fmaxf(acc1[4*T+0], 0.f), h1 = fmaxf(acc1[4*T+1], 0.f);
                float h2 = fmaxf(acc1[4*T+2], 0.f), h3 = fmaxf(acc1[4*T+3], 0.f);
                Phi[2*T+0] = packhi(h0, h1);
                Phi[2*T+1] = packhi(h2, h3);
                Plo[2*T+0] = packhi(remf(h0), remf(h1));
                Plo[2*T+1] = packhi(remf(h2), remf(h3));
            }

            // half-swap -> GEMM2 A-fragments (lane = pixel row, k = hidden)
            #pragma unroll
            for (int c = 0; c < 2; ++c) {
                unsigned fa0 = Phi[(2*c)*2+0], fb0 = Phi[(2*c+1)*2+0];
                unsigned fa1 = Phi[(2*c)*2+1], fb1 = Phi[(2*c+1)*2+1];
                asm volatile("v_permlane32_swap_b32 %0, %1" : "+v"(fa0), "+v"(fb0));
                asm volatile("v_permlane32_swap_b32 %0, %1" : "+v"(fa1), "+v"(fb1));
                unsigned la0 = Plo[(2*c)*2+0], lb0 = Plo[(2*c+1)*2+0];
                unsigned la1 = Plo[(2*c)*2+1], lb1 = Plo[(2*c+1)*2+1];
                asm volatile("v_permlane32_swap_b32 %0, %1" : "+v"(la0), "+v"(lb0));
                asm volatile("v_permlane32_swap_b32 %0, %1" : "+v"(la1), "+v"(lb1));
                uint4v hv_ = { fa0, fa1, fb0, fb1 };
                uint4v lv_ = { la0, la1, lb0, lb1 };
                bf16x8 A2h = __builtin_bit_cast(bf16x8, hv_);
                bf16x8 A2l = __builtin_bit_cast(bf16x8, lv_);

                const int g = (og*2 + c)*2;
                bf16x8 w2h = __builtin_bit_cast(bf16x8, ld8(w2ai + (g + 0)*512));
                bf16x8 w2l = __builtin_bit_cast(bf16x8, ld8(w2ai + (g + 1)*512));
                acc2 = MFMA(A2h, w2h, acc2);
                acc2 = MFMA(A2h, w2l, acc2);
                acc2 = MFMA(A2l, w2h, acc2);
            }
        }

        // ---- store: lane ol(<16) = out-channel; regs = 16 pixels as 4x float4 ----
        if (v16) {
            const int ob = (b*16 + ol)*65536 + y*256 + x0 + half*4;
            #pragma unroll
            for (int c = 0; c < 4; ++c) {
                f32x4 v = { acc2[4*c+0], acc2[4*c+1], acc2[4*c+2], acc2[4*c+3] };
                *(f32x4*)&out[ob + c*8] = v;
            }
        }
    }
}

extern "C" void kernel_launch(void* const* d_in, const int* in_sizes, int n_in,
                              void* d_out, int out_size, void* d_ws, size_t ws_size,
                              hipStream_t stream) {
    const float* grid = (const float*)d_in[0];
    const float* W1   = (const float*)d_in[1];
    const float* b1   = (const float*)d_in[2];
    const float* W2   = (const float*)d_in[3];
    const float* b2   = (const float*)d_in[4];
    float* out = (float*)d_out;

    // 1024 blocks x 512 threads = 8192 waves; each wave: 4 tiles of 32 pixels
    nca_mfma6_kernel<<<1024, 512, 0, stream>>>(grid, W1, b1, W2, b2, out);
}